// Round 1
// baseline (2796.161 us; speedup 1.0000x reference)
//
#include <hip/hip_runtime.h>

#define NBUS 118
#define BATCH 4096
#define NNODES (BATCH * NBUS)          // 483328
#define END_EDGES (4 * NNODES)         // 1933312
#define E_EDGES (END_EDGES + NNODES)   // 2416640
#define NLAYERS 10

// K0: p = x0 - x1; denomInv = 1/(diag(ybus)*100); zero aggrA, aggrB, err slots.
__global__ void init_kernel(const float* __restrict__ x,
                            const float* __restrict__ ybus,
                            float* __restrict__ p,
                            float* __restrict__ denomInv,
                            float* __restrict__ aggrA,
                            float* __restrict__ aggrB,
                            float* __restrict__ errOut /* NLAYERS+1 slots */) {
    int tid = blockIdx.x * blockDim.x + threadIdx.x;
    int stride = gridDim.x * blockDim.x;
    for (int i = tid; i < NNODES; i += stride) {
        float2 xi = ((const float2*)x)[i];
        p[i] = xi.x - xi.y;
        int b = i / NBUS;
        int j = i - b * NBUS;
        denomInv[i] = 1.0f / (ybus[b * (NBUS * NBUS) + j * (NBUS + 1)] * 100.0f);
        aggrA[i] = 0.0f;
        aggrB[i] = 0.0f;
    }
    if (tid < NLAYERS + 1) errOut[tid] = 0.0f;
}

// O_k: out = (p - aggr)*denomInv, minus slack (value at column 0 of each batch row).
// One 128-thread block per batch row. Also zeroes zeroBuf (aggrB for next lc scatter).
__global__ void out_kernel(const float* __restrict__ p,
                           const float* __restrict__ aggr,
                           const float* __restrict__ denomInv,
                           float* __restrict__ out,
                           float* __restrict__ zeroBuf) {
    int b = blockIdx.x;
    int j = threadIdx.x;
    __shared__ float v0s;
    int i = b * NBUS + j;
    float v = 0.0f;
    if (j < NBUS) v = (p[i] - aggr[i]) * denomInv[i];
    if (j == 0) v0s = v;
    __syncthreads();
    if (j < NBUS) out[i] = v - v0s;
    // fused zeroing of the other aggregation buffer (disjoint from everything above)
    int t = b * blockDim.x + threadIdx.x;
    if (t < NNODES) zeroBuf[t] = 0.0f;
}

// Scatter: aggr[dst[e]] += theta[src[e]] * ew[e] * 100 (atomic), 4 edges/thread/step.
// Optionally fused: err reduction sum|p - aggrPrev| -> atomicAdd(errSlot)  [disjoint arrays]
// Optionally fused: zero zeroBuf                                           [disjoint array]
template <bool DO_ERR>
__global__ void scatter_kernel(const int* __restrict__ src,
                               const int* __restrict__ dst,
                               const float* __restrict__ ew,
                               const float* __restrict__ theta,
                               float* __restrict__ aggr,
                               int E4,
                               const float* __restrict__ p,
                               const float* __restrict__ aggrPrev,
                               float* __restrict__ errSlot,
                               float* __restrict__ zeroBuf) {
    int tid = blockIdx.x * blockDim.x + threadIdx.x;
    int stride = gridDim.x * blockDim.x;

    for (int e = tid; e < E4; e += stride) {
        int4 s = ((const int4*)src)[e];
        int4 d = ((const int4*)dst)[e];
        float4 w = ((const float4*)ew)[e];
        atomicAdd(&aggr[d.x], theta[s.x] * (w.x * 100.0f));
        atomicAdd(&aggr[d.y], theta[s.y] * (w.y * 100.0f));
        atomicAdd(&aggr[d.z], theta[s.z] * (w.z * 100.0f));
        atomicAdd(&aggr[d.w], theta[s.w] * (w.w * 100.0f));
    }

    if (zeroBuf) {
        for (int i = tid; i < NNODES; i += stride) zeroBuf[i] = 0.0f;
    }

    if (DO_ERR) {
        float acc = 0.0f;
        for (int i = tid; i < NNODES / 4; i += stride) {
            float4 pv = ((const float4*)p)[i];
            float4 av = ((const float4*)aggrPrev)[i];
            acc += fabsf(pv.x - av.x) + fabsf(pv.y - av.y) +
                   fabsf(pv.z - av.z) + fabsf(pv.w - av.w);
        }
        for (int off = 32; off > 0; off >>= 1) acc += __shfl_down(acc, off, 64);
        __shared__ float ws[4];
        int lane = threadIdx.x & 63;
        int wid = threadIdx.x >> 6;
        if (lane == 0) ws[wid] = acc;
        __syncthreads();
        if (threadIdx.x == 0) {
            atomicAdd(errSlot, ws[0] + ws[1] + ws[2] + ws[3]);
        }
    }
}

extern "C" void kernel_launch(void* const* d_in, const int* in_sizes, int n_in,
                              void* d_out, int out_size, void* d_ws, size_t ws_size,
                              hipStream_t stream) {
    const float* x     = (const float*)d_in[0];
    // d_in[1] = y, unused (only its shape/zeros matter)
    const int*   ei_nd = (const int*)d_in[2];
    const float* ea_nd = (const float*)d_in[3];
    const int*   ei    = (const int*)d_in[4];
    const float* ea    = (const float*)d_in[5];
    const float* ybus  = (const float*)d_in[6];

    float* out_f = (float*)d_out;
    float* errs  = out_f + NNODES;

    float* ws       = (float*)d_ws;
    float* p        = ws + 0LL * NNODES;
    float* denomInv = ws + 1LL * NNODES;
    float* aggrA    = ws + 2LL * NNODES;  // gpg_layer aggregation
    float* aggrB    = ws + 3LL * NNODES;  // lc_error aggregation
    float* outA     = ws + 4LL * NNODES;
    float* outB     = ws + 5LL * NNODES;

    const int* src_nd = ei_nd;
    const int* dst_nd = ei_nd + END_EDGES;
    const int* src_f  = ei;
    const int* dst_f  = ei + E_EDGES;

    init_kernel<<<1024, 256, 0, stream>>>(x, ybus, p, denomInv, aggrA, aggrB, errs);

    // Layer 0: theta = 0 -> aggr = 0; out0 = p*denomInv - slack
    out_kernel<<<BATCH, 128, 0, stream>>>(p, aggrA, denomInv, outA, aggrB);
    // SF_0: scatter_full(out0 -> aggrB); (re)zero aggrA
    scatter_kernel<false><<<2048, 256, 0, stream>>>(
        src_f, dst_f, ea, outA, aggrB, E_EDGES / 4,
        nullptr, nullptr, nullptr, aggrA);

    const float* cur = outA;
    for (int k = 1; k <= NLAYERS; ++k) {
        float* nxt = (k == NLAYERS) ? out_f : ((k & 1) ? outB : outA);
        // SN_k: scatter_nd(cur -> aggrA)  +  err_{k-1} = sum|p - aggrB|
        scatter_kernel<true><<<2048, 256, 0, stream>>>(
            src_nd, dst_nd, ea_nd, cur, aggrA, END_EDGES / 4,
            p, aggrB, errs + (k - 1), nullptr);
        // O_k: out_k = (p - aggrA)*denomInv - slack;  zero aggrB
        out_kernel<<<BATCH, 128, 0, stream>>>(p, aggrA, denomInv, nxt, aggrB);
        // SF_k: scatter_full(out_k -> aggrB);  zero aggrA
        scatter_kernel<false><<<2048, 256, 0, stream>>>(
            src_f, dst_f, ea, nxt, aggrB, E_EDGES / 4,
            nullptr, nullptr, nullptr, aggrA);
        cur = nxt;
    }
    // Final error reduce (E4 = 0 -> scatter loop skipped)
    scatter_kernel<true><<<1024, 256, 0, stream>>>(
        src_nd, dst_nd, ea_nd, cur, aggrA, 0,
        p, aggrB, errs + NLAYERS, nullptr);
}

// Round 2
// 1712.749 us; speedup vs baseline: 1.6326x; 1.6326x over previous
//
#include <hip/hip_runtime.h>

#define NBUS 118
#define BATCH 4096
#define NN (BATCH * NBUS)          // 483328 nodes
#define END_E (4 * NN)             // 1933312 no-diag edges
#define EF_E (END_E + NN)          // 2416640 full edges
#define NLAYERS 10
#define SCAN_BLOCKS (NN / 256)     // 1888 (exact)

// ---------- K1: p, denomInv, zero histograms + err slots ----------
__global__ void init_kernel(const float* __restrict__ x,
                            const float* __restrict__ ybus,
                            float* __restrict__ p,
                            float* __restrict__ denomInv,
                            int* __restrict__ cnt_nd,
                            int* __restrict__ cnt_f,
                            float* __restrict__ errOut) {
    int tid = blockIdx.x * blockDim.x + threadIdx.x;
    int stride = gridDim.x * blockDim.x;
    for (int i = tid; i < NN; i += stride) {
        float2 xi = ((const float2*)x)[i];
        p[i] = xi.x - xi.y;
        int b = i / NBUS;
        int j = i - b * NBUS;
        denomInv[i] = 1.0f / (ybus[b * (NBUS * NBUS) + j * (NBUS + 1)] * 100.0f);
        cnt_nd[i] = 0;
        cnt_f[i] = 0;
    }
    if (tid < NLAYERS + 1) errOut[tid] = 0.0f;
}

// ---------- K2: histogram of dst for both edge sets ----------
__global__ void hist_kernel(const int* __restrict__ dst_nd,
                            const int* __restrict__ dst_f,
                            int* __restrict__ cnt_nd,
                            int* __restrict__ cnt_f) {
    int tid = blockIdx.x * blockDim.x + threadIdx.x;
    int stride = gridDim.x * blockDim.x;
    for (int e = tid; e < EF_E; e += stride) {
        if (e < END_E) atomicAdd(&cnt_nd[dst_nd[e]], 1);
        atomicAdd(&cnt_f[dst_f[e]], 1);
    }
}

// ---------- K3: per-block exclusive scan (256 elems/block) ----------
__global__ void scan_block_kernel(const int* __restrict__ cnt,
                                  int* __restrict__ start,
                                  int* __restrict__ bs) {
    __shared__ int sd[256];
    int tid = threadIdx.x;
    int gid = blockIdx.x * 256 + tid;
    int v = cnt[gid];
    sd[tid] = v;
    __syncthreads();
    for (int off = 1; off < 256; off <<= 1) {
        int t = (tid >= off) ? sd[tid - off] : 0;
        __syncthreads();
        sd[tid] += t;
        __syncthreads();
    }
    start[gid] = sd[tid] - v;                 // exclusive
    if (tid == 255) bs[blockIdx.x] = sd[255]; // block total
}

// ---------- K4: scan the 1888 block sums in-place (single block) ----------
__global__ void scan_sums_kernel(int* __restrict__ bs, int nblk) {
    __shared__ int sd[256];
    __shared__ int run;
    int tid = threadIdx.x;
    if (tid == 0) run = 0;
    __syncthreads();
    for (int base = 0; base < nblk; base += 256) {
        int idx = base + tid;
        int v = (idx < nblk) ? bs[idx] : 0;
        sd[tid] = v;
        __syncthreads();
        for (int off = 1; off < 256; off <<= 1) {
            int t = (tid >= off) ? sd[tid - off] : 0;
            __syncthreads();
            sd[tid] += t;
            __syncthreads();
        }
        int incl = sd[tid];
        int chunk_total = sd[255];
        int outv = incl - v + run;
        if (idx < nblk) bs[idx] = outv;
        __syncthreads();
        if (tid == 0) run += chunk_total;
        __syncthreads();
    }
}

// ---------- K5: add block offsets; start -> row starts; init cursors ----------
__global__ void scan_add_kernel(int* __restrict__ start,
                                const int* __restrict__ bs,
                                int* __restrict__ cursor,
                                int total) {
    int gid = blockIdx.x * blockDim.x + threadIdx.x;
    if (gid < NN) {
        int v = start[gid] + bs[gid >> 8];
        start[gid] = v;
        cursor[gid] = v;
    }
    if (gid == 0) start[NN] = total;
}

// ---------- K6: permutation scatter -> CSR (src, w*100) pairs ----------
__global__ void permute_kernel(const int* __restrict__ src_nd,
                               const int* __restrict__ dst_nd,
                               const float* __restrict__ ea_nd,
                               const int* __restrict__ src_f,
                               const int* __restrict__ dst_f,
                               const float* __restrict__ ea_f,
                               int* __restrict__ cursor_nd,
                               int* __restrict__ cursor_f,
                               int2* __restrict__ perm_nd,
                               int2* __restrict__ perm_f) {
    int tid = blockIdx.x * blockDim.x + threadIdx.x;
    int stride = gridDim.x * blockDim.x;
    for (int e = tid; e < EF_E; e += stride) {
        if (e < END_E) {
            int d = dst_nd[e];
            int pos = atomicAdd(&cursor_nd[d], 1);
            perm_nd[pos] = make_int2(src_nd[e], __float_as_int(ea_nd[e] * 100.0f));
        }
        int d = dst_f[e];
        int pos = atomicAdd(&cursor_f[d], 1);
        perm_f[pos] = make_int2(src_f[e], __float_as_int(ea_f[e] * 100.0f));
    }
}

// ---------- K7: layer 0 (theta = 0): out0 = p*denomInv - slack ----------
__global__ void out0_kernel(const float* __restrict__ p,
                            const float* __restrict__ denomInv,
                            float* __restrict__ out) {
    int b = blockIdx.x;
    int j = threadIdx.x;
    int i = b * NBUS + j;
    __shared__ float z0;
    float z = 0.0f;
    if (j < NBUS) z = p[i] * denomInv[i];
    if (j == 0) z0 = z;
    __syncthreads();
    if (j < NBUS) out[i] = z - z0;
}

// ---------- K8: fused layer: gather-nd -> out_k ; gather-f -> err_{k-1} ----------
template <bool DO_OUT>
__global__ void layer_kernel(const int* __restrict__ start_nd,
                             const int2* __restrict__ perm_nd,
                             const int* __restrict__ start_f,
                             const int2* __restrict__ perm_f,
                             const float* __restrict__ cur,
                             const float* __restrict__ p,
                             const float* __restrict__ denomInv,
                             float* __restrict__ out,
                             float* __restrict__ errSlot) {
    int b = blockIdx.x;
    int j = threadIdx.x;
    int i = b * NBUS + j;
    bool act = j < NBUS;
    __shared__ float z0;
    __shared__ float ws2[2];

    float pv = 0.0f, di = 0.0f;
    float sum_nd = 0.0f, sum_f = 0.0f;
    if (act) {
        pv = p[i];
        if (DO_OUT) {
            di = denomInv[i];
            int s = start_nd[i], e = start_nd[i + 1];
            for (int t = s; t < e; ++t) {
                int2 pr = perm_nd[t];
                sum_nd += cur[pr.x] * __int_as_float(pr.y);
            }
        }
        int s = start_f[i], e = start_f[i + 1];
        for (int t = s; t < e; ++t) {
            int2 pr = perm_f[t];
            sum_f += cur[pr.x] * __int_as_float(pr.y);
        }
    }
    if (DO_OUT) {
        float z = (pv - sum_nd) * di;
        if (j == 0) z0 = z;
        __syncthreads();
        if (act) out[i] = z - z0;
    }
    float acc = act ? fabsf(pv - sum_f) : 0.0f;
    for (int off = 32; off > 0; off >>= 1) acc += __shfl_down(acc, off, 64);
    if ((threadIdx.x & 63) == 0) ws2[threadIdx.x >> 6] = acc;
    __syncthreads();
    if (threadIdx.x == 0) atomicAdd(errSlot, ws2[0] + ws2[1]);
}

extern "C" void kernel_launch(void* const* d_in, const int* in_sizes, int n_in,
                              void* d_out, int out_size, void* d_ws, size_t ws_size,
                              hipStream_t stream) {
    const float* x     = (const float*)d_in[0];
    const int*   ei_nd = (const int*)d_in[2];
    const float* ea_nd = (const float*)d_in[3];
    const int*   ei    = (const int*)d_in[4];
    const float* ea    = (const float*)d_in[5];
    const float* ybus  = (const float*)d_in[6];

    float* out_f = (float*)d_out;
    float* errs  = out_f + NN;

    // workspace carve (4-byte units; all offsets even -> int2 alignment ok)
    float* wsf      = (float*)d_ws;
    float* p        = wsf;                  wsf += NN;
    float* denomInv = wsf;                  wsf += NN;
    float* outA     = wsf;                  wsf += NN;
    float* outB     = wsf;                  wsf += NN;
    int*   start_nd = (int*)wsf;            wsf += NN + 2;
    int*   start_f  = (int*)wsf;            wsf += NN + 2;
    int*   cur_nd   = (int*)wsf;            wsf += NN;   // histogram counts, then cursors
    int*   cur_f    = (int*)wsf;            wsf += NN;
    int*   bs_nd    = (int*)wsf;            wsf += 2048;
    int*   bs_f     = (int*)wsf;            wsf += 2048;
    int2*  perm_nd  = (int2*)wsf;           wsf += 2LL * END_E;
    int2*  perm_f   = (int2*)wsf;           wsf += 2LL * EF_E;

    const int* src_nd = ei_nd;
    const int* dst_nd = ei_nd + END_E;
    const int* src_f  = ei;
    const int* dst_f  = ei + EF_E;

    // ---- build phase ----
    init_kernel<<<1024, 256, 0, stream>>>(x, ybus, p, denomInv, cur_nd, cur_f, errs);
    hist_kernel<<<2048, 256, 0, stream>>>(dst_nd, dst_f, cur_nd, cur_f);
    scan_block_kernel<<<SCAN_BLOCKS, 256, 0, stream>>>(cur_nd, start_nd, bs_nd);
    scan_block_kernel<<<SCAN_BLOCKS, 256, 0, stream>>>(cur_f, start_f, bs_f);
    scan_sums_kernel<<<1, 256, 0, stream>>>(bs_nd, SCAN_BLOCKS);
    scan_sums_kernel<<<1, 256, 0, stream>>>(bs_f, SCAN_BLOCKS);
    scan_add_kernel<<<SCAN_BLOCKS, 256, 0, stream>>>(start_nd, bs_nd, cur_nd, END_E);
    scan_add_kernel<<<SCAN_BLOCKS, 256, 0, stream>>>(start_f, bs_f, cur_f, EF_E);
    permute_kernel<<<2048, 256, 0, stream>>>(src_nd, dst_nd, ea_nd, src_f, dst_f, ea,
                                             cur_nd, cur_f, perm_nd, perm_f);

    // ---- iterate phase ----
    out0_kernel<<<BATCH, 128, 0, stream>>>(p, denomInv, outA);
    const float* cur = outA;
    for (int k = 1; k <= NLAYERS; ++k) {
        float* nxt = (k == NLAYERS) ? out_f : ((k & 1) ? outB : outA);
        // computes err_{k-1} from cur AND out_k from cur
        layer_kernel<true><<<BATCH, 128, 0, stream>>>(
            start_nd, perm_nd, start_f, perm_f, cur, p, denomInv, nxt, errs + (k - 1));
        cur = nxt;
    }
    // final error err_10 on out_10 (= d_out nodes)
    layer_kernel<false><<<BATCH, 128, 0, stream>>>(
        start_nd, perm_nd, start_f, perm_f, cur, p, denomInv, nullptr, errs + NLAYERS);
}

// Round 3
// 1331.618 us; speedup vs baseline: 2.0998x; 1.2862x over previous
//
#include <hip/hip_runtime.h>

#define NBUS 118
#define BATCH 4096
#define NN (BATCH * NBUS)          // 483328 nodes
#define END_E (4 * NN)             // 1933312 no-diag edges
#define EF_E (END_E + NN)          // 2416640 full edges
#define NLAYERS 10

#define NBKT 236                   // coarse dst buckets, span 2048: 236*2048 == NN
#define SPAN_SHIFT 11
#define SPAN_MASK 2047
#define TILE 4096                  // edges per binA block
#define ND_TILES (END_E / TILE)    // 472 (exact)
#define F_TILES  (EF_E / TILE)     // 590 (exact)
#define CAP_ND 8960                // avg 8192, sigma~90 -> +8.5 sigma pad
#define CAP_F  11008               // avg 10240, sigma~101 -> +7.6 sigma pad

// ---------- K1: p, denomInv, err slots, bucket cursors ----------
__global__ void init_kernel(const float* __restrict__ x,
                            const float* __restrict__ ybus,
                            float* __restrict__ p,
                            float* __restrict__ denomInv,
                            int* __restrict__ cursor_nd,
                            int* __restrict__ cursor_f,
                            float* __restrict__ errOut) {
    int tid = blockIdx.x * blockDim.x + threadIdx.x;
    int stride = gridDim.x * blockDim.x;
    for (int i = tid; i < NN; i += stride) {
        float2 xi = ((const float2*)x)[i];
        p[i] = xi.x - xi.y;
        int b = i / NBUS;
        int j = i - b * NBUS;
        denomInv[i] = 1.0f / (ybus[b * (NBUS * NBUS) + j * (NBUS + 1)] * 100.0f);
    }
    if (tid < 256) {
        cursor_nd[tid] = tid * CAP_ND;
        cursor_f[tid]  = tid * CAP_F;
    }
    if (tid < NLAYERS + 1) errOut[tid] = 0.0f;
}

// ---------- K2 (binA): tile -> LDS bin by coarse bucket -> chunked staging writes ----------
// staged entry: .x = src | (dstLocal<<19), .y = bits(w*100)
__global__ __launch_bounds__(256) void binA_kernel(
        const int* __restrict__ src_nd, const int* __restrict__ dst_nd,
        const float* __restrict__ ea_nd,
        const int* __restrict__ src_f, const int* __restrict__ dst_f,
        const float* __restrict__ ea_f,
        int* __restrict__ cursor_nd, int* __restrict__ cursor_f,
        uint2* __restrict__ stg_nd, uint2* __restrict__ stg_f) {
    __shared__ uint2 buf[TILE];            // 32 KB
    __shared__ unsigned char sb[TILE];     // 4 KB, slot -> bucket
    __shared__ int hist[256];              // counts -> scatter cursors
    __shared__ int scanA[256];             // scan scratch (incl)
    __shared__ int segStart[256];          // immutable excl
    __shared__ int segGBase[256];          // global base from atomic

    bool isF = blockIdx.x >= ND_TILES;
    int tile = isF ? (blockIdx.x - ND_TILES) : blockIdx.x;
    const int* src = isF ? src_f : src_nd;
    const int* dst = isF ? dst_f : dst_nd;
    const float* ea = isF ? ea_f : ea_nd;
    int* cursor = isF ? cursor_f : cursor_nd;
    uint2* stg = isF ? stg_f : stg_nd;
    int cap = isF ? CAP_F : CAP_ND;

    int tid = threadIdx.x;
    int base = tile * TILE;

    hist[tid] = 0;
    __syncthreads();

    // pass 1: histogram of coarse buckets
    #pragma unroll
    for (int k = 0; k < TILE / 256; ++k) {
        int d = dst[base + k * 256 + tid];
        atomicAdd(&hist[d >> SPAN_SHIFT], 1);
    }
    __syncthreads();

    // exclusive scan of 256 bucket counts (Hillis-Steele inclusive, then -cnt)
    int cnt = hist[tid];
    scanA[tid] = cnt;
    __syncthreads();
    for (int off = 1; off < 256; off <<= 1) {
        int t = (tid >= off) ? scanA[tid - off] : 0;
        __syncthreads();
        scanA[tid] += t;
        __syncthreads();
    }
    int excl = scanA[tid] - cnt;
    segStart[tid] = excl;
    hist[tid] = excl;  // becomes LDS scatter cursor
    if (tid < NBKT && cnt > 0) segGBase[tid] = atomicAdd(&cursor[tid], cnt);
    __syncthreads();

    // pass 2: scatter tile into LDS, segment-ordered
    #pragma unroll
    for (int k = 0; k < TILE / 256; ++k) {
        int e = base + k * 256 + tid;
        int d = dst[e];
        int bkt = d >> SPAN_SHIFT;
        int pos = atomicAdd(&hist[bkt], 1);
        unsigned dl = (unsigned)(d & SPAN_MASK);
        buf[pos] = make_uint2((unsigned)src[e] | (dl << 19),
                              (unsigned)__float_as_int(ea[e] * 100.0f));
        sb[pos] = (unsigned char)bkt;
    }
    __syncthreads();

    // pass 3: coalesced-ish flush: each LDS segment -> contiguous global chunk
    #pragma unroll
    for (int k = 0; k < TILE / 256; ++k) {
        int slot = k * 256 + tid;
        int bkt = sb[slot];
        int gpos = segGBase[bkt] + (slot - segStart[bkt]);
        if (gpos < (bkt + 1) * cap)  // freak-overflow guard
            stg[gpos] = buf[slot];
    }
}

// ---------- K3: scan bucket counts -> dense CSR bases; sentinels ----------
__global__ void bucket_base_kernel(const int* __restrict__ cursor_nd,
                                   const int* __restrict__ cursor_f,
                                   int* __restrict__ base_nd,
                                   int* __restrict__ base_f,
                                   int* __restrict__ start_nd,
                                   int* __restrict__ start_f) {
    __shared__ int sd[256];
    int tid = threadIdx.x;
    // --- nd ---
    int c = 0;
    if (tid < NBKT) {
        c = cursor_nd[tid] - tid * CAP_ND;
        if (c > CAP_ND) c = CAP_ND;
    }
    sd[tid] = c;
    __syncthreads();
    for (int off = 1; off < 256; off <<= 1) {
        int t = (tid >= off) ? sd[tid - off] : 0;
        __syncthreads();
        sd[tid] += t;
        __syncthreads();
    }
    if (tid < NBKT) base_nd[tid] = sd[tid] - c;
    __syncthreads();
    // --- f ---
    if (tid < NBKT) {
        c = cursor_f[tid] - tid * CAP_F;
        if (c > CAP_F) c = CAP_F;
    } else c = 0;
    sd[tid] = c;
    __syncthreads();
    for (int off = 1; off < 256; off <<= 1) {
        int t = (tid >= off) ? sd[tid - off] : 0;
        __syncthreads();
        sd[tid] += t;
        __syncthreads();
    }
    if (tid < NBKT) base_f[tid] = sd[tid] - c;
    if (tid == 0) {
        start_nd[NN] = END_E;
        start_f[NN] = EF_E;
    }
}

// ---------- K4 (binB): per-bucket CSR build (L2-resident region) ----------
__global__ __launch_bounds__(256) void binB_kernel(
        const uint2* __restrict__ stg_nd, const uint2* __restrict__ stg_f,
        const int* __restrict__ cursor_nd, const int* __restrict__ cursor_f,
        const int* __restrict__ base_nd, const int* __restrict__ base_f,
        int* __restrict__ start_nd, int* __restrict__ start_f,
        int2* __restrict__ perm_nd, int2* __restrict__ perm_f) {
    __shared__ int h[2048];       // local-node hist -> excl -> cursor
    __shared__ int partial[256];

    bool isF = blockIdx.x >= NBKT;
    int bb = isF ? (blockIdx.x - NBKT) : blockIdx.x;
    const uint2* stg = isF ? stg_f : stg_nd;
    int cap = isF ? CAP_F : CAP_ND;
    int cnt = (isF ? cursor_f[bb] : cursor_nd[bb]) - bb * cap;
    if (cnt > cap) cnt = cap;
    int denseBase = isF ? base_f[bb] : base_nd[bb];
    int* start = isF ? start_f : start_nd;
    int2* perm = isF ? perm_f : perm_nd;
    int stgBase = bb * cap;
    int tid = threadIdx.x;

    #pragma unroll
    for (int k = 0; k < 8; ++k) h[k * 256 + tid] = 0;
    __syncthreads();

    // phase 1: local-node histogram
    for (int i = tid; i < cnt; i += 256) {
        uint2 v = stg[stgBase + i];
        atomicAdd(&h[(v.x >> 19) & SPAN_MASK], 1);
    }
    __syncthreads();

    // phase 2: exclusive scan of 2048 (8 per thread, consecutive)
    int loc[8];
    int s = 0;
    #pragma unroll
    for (int k = 0; k < 8; ++k) { loc[k] = h[tid * 8 + k]; s += loc[k]; }
    partial[tid] = s;
    __syncthreads();
    for (int off = 1; off < 256; off <<= 1) {
        int t = (tid >= off) ? partial[tid - off] : 0;
        __syncthreads();
        partial[tid] += t;
        __syncthreads();
    }
    int run = partial[tid] - s;  // exclusive over thread chunks
    #pragma unroll
    for (int k = 0; k < 8; ++k) { int c = loc[k]; h[tid * 8 + k] = run; run += c; }
    __syncthreads();

    // phase 3: write start[] coalesced (h currently holds excl offsets)
    int nodeBase = bb * 2048;
    #pragma unroll
    for (int k = 0; k < 8; ++k) {
        int l = k * 256 + tid;
        start[nodeBase + l] = denseBase + h[l];
    }
    __syncthreads();

    // phase 4: scatter staged -> dense CSR (random within L2-resident region)
    for (int i = tid; i < cnt; i += 256) {
        uint2 v = stg[stgBase + i];
        int dl = (v.x >> 19) & SPAN_MASK;
        int pos = denseBase + atomicAdd(&h[dl], 1);
        perm[pos] = make_int2((int)(v.x & 0x7FFFF), (int)v.y);
    }
}

// ---------- K5: layer 0 (theta = 0): out0 = p*denomInv - slack ----------
__global__ void out0_kernel(const float* __restrict__ p,
                            const float* __restrict__ denomInv,
                            float* __restrict__ out) {
    int b = blockIdx.x;
    int j = threadIdx.x;
    int i = b * NBUS + j;
    __shared__ float z0;
    float z = 0.0f;
    if (j < NBUS) z = p[i] * denomInv[i];
    if (j == 0) z0 = z;
    __syncthreads();
    if (j < NBUS) out[i] = z - z0;
}

// ---------- K6: fused layer: gather-nd -> out_k ; gather-f -> err_{k-1} ----------
template <bool DO_OUT>
__global__ void layer_kernel(const int* __restrict__ start_nd,
                             const int2* __restrict__ perm_nd,
                             const int* __restrict__ start_f,
                             const int2* __restrict__ perm_f,
                             const float* __restrict__ cur,
                             const float* __restrict__ p,
                             const float* __restrict__ denomInv,
                             float* __restrict__ out,
                             float* __restrict__ errSlot) {
    int b = blockIdx.x;
    int j = threadIdx.x;
    int i = b * NBUS + j;
    bool act = j < NBUS;
    __shared__ float z0;
    __shared__ float ws2[2];

    float pv = 0.0f, di = 0.0f;
    float sum_nd = 0.0f, sum_f = 0.0f;
    if (act) {
        pv = p[i];
        if (DO_OUT) {
            di = denomInv[i];
            int s = start_nd[i], e = start_nd[i + 1];
            for (int t = s; t < e; ++t) {
                int2 pr = perm_nd[t];
                sum_nd += cur[pr.x] * __int_as_float(pr.y);
            }
        }
        int s = start_f[i], e = start_f[i + 1];
        for (int t = s; t < e; ++t) {
            int2 pr = perm_f[t];
            sum_f += cur[pr.x] * __int_as_float(pr.y);
        }
    }
    if (DO_OUT) {
        float z = (pv - sum_nd) * di;
        if (j == 0) z0 = z;
        __syncthreads();
        if (act) out[i] = z - z0;
    }
    float acc = act ? fabsf(pv - sum_f) : 0.0f;
    for (int off = 32; off > 0; off >>= 1) acc += __shfl_down(acc, off, 64);
    if ((threadIdx.x & 63) == 0) ws2[threadIdx.x >> 6] = acc;
    __syncthreads();
    if (threadIdx.x == 0) atomicAdd(errSlot, ws2[0] + ws2[1]);
}

extern "C" void kernel_launch(void* const* d_in, const int* in_sizes, int n_in,
                              void* d_out, int out_size, void* d_ws, size_t ws_size,
                              hipStream_t stream) {
    const float* x     = (const float*)d_in[0];
    const int*   ei_nd = (const int*)d_in[2];
    const float* ea_nd = (const float*)d_in[3];
    const int*   ei    = (const int*)d_in[4];
    const float* ea    = (const float*)d_in[5];
    const float* ybus  = (const float*)d_in[6];

    float* out_f = (float*)d_out;
    float* errs  = out_f + NN;

    // workspace carve (4-byte units; every region even-sized -> 8B alignment holds)
    float* wsf       = (float*)d_ws;
    float* p         = wsf;          wsf += NN;
    float* denomInv  = wsf;          wsf += NN;
    float* outA      = wsf;          wsf += NN;
    float* outB      = wsf;          wsf += NN;
    int*   start_nd  = (int*)wsf;    wsf += NN + 2;
    int*   start_f   = (int*)wsf;    wsf += NN + 2;
    int*   cursor_nd = (int*)wsf;    wsf += 256;
    int*   cursor_f  = (int*)wsf;    wsf += 256;
    int*   base_nd   = (int*)wsf;    wsf += 256;
    int*   base_f    = (int*)wsf;    wsf += 256;
    int2*  perm_nd   = (int2*)wsf;   wsf += 2LL * END_E;
    int2*  perm_f    = (int2*)wsf;   wsf += 2LL * EF_E;
    uint2* stg_nd    = (uint2*)wsf;  wsf += 2LL * NBKT * CAP_ND;
    uint2* stg_f     = (uint2*)wsf;  wsf += 2LL * NBKT * CAP_F;

    const int* src_nd = ei_nd;
    const int* dst_nd = ei_nd + END_E;
    const int* src_f  = ei;
    const int* dst_f  = ei + EF_E;

    // ---- build phase ----
    init_kernel<<<1024, 256, 0, stream>>>(x, ybus, p, denomInv, cursor_nd, cursor_f, errs);
    binA_kernel<<<ND_TILES + F_TILES, 256, 0, stream>>>(
        src_nd, dst_nd, ea_nd, src_f, dst_f, ea,
        cursor_nd, cursor_f, stg_nd, stg_f);
    bucket_base_kernel<<<1, 256, 0, stream>>>(cursor_nd, cursor_f,
                                              base_nd, base_f, start_nd, start_f);
    binB_kernel<<<2 * NBKT, 256, 0, stream>>>(
        stg_nd, stg_f, cursor_nd, cursor_f, base_nd, base_f,
        start_nd, start_f, perm_nd, perm_f);

    // ---- iterate phase ----
    out0_kernel<<<BATCH, 128, 0, stream>>>(p, denomInv, outA);
    const float* cur = outA;
    for (int k = 1; k <= NLAYERS; ++k) {
        float* nxt = (k == NLAYERS) ? out_f : ((k & 1) ? outB : outA);
        layer_kernel<true><<<BATCH, 128, 0, stream>>>(
            start_nd, perm_nd, start_f, perm_f, cur, p, denomInv, nxt, errs + (k - 1));
        cur = nxt;
    }
    layer_kernel<false><<<BATCH, 128, 0, stream>>>(
        start_nd, perm_nd, start_f, perm_f, cur, p, denomInv, nullptr, errs + NLAYERS);
}

// Round 4
// 1299.279 us; speedup vs baseline: 2.1521x; 1.0249x over previous
//
#include <hip/hip_runtime.h>

#define NBUS 118
#define BATCH 4096
#define NN (BATCH * NBUS)          // 483328 nodes
#define END_E (4 * NN)             // 1933312 no-diag edges
#define EF_E (END_E + NN)          // 2416640 full edges
#define NLAYERS 10

#define NBKT 236                   // coarse dst buckets, span 2048: 236*2048 == NN
#define SPAN_SHIFT 11
#define SPAN_MASK 2047
#define TILE 4096                  // edges per binA block
#define ND_TILES (END_E / TILE)    // 472 (exact)
#define F_TILES  (EF_E / TILE)     // 590 (exact)
#define CAP_ND 8960                // avg 8192 per bucket, +8.5 sigma pad
#define CAP_F  11008               // avg 10240 per bucket, +7.6 sigma pad

#define W_ND 8                     // ELL width (slot W-1 doubles as tail descriptor)
#define W_F 9
#define TAILCAP 1048576            // entries per tail array (expected ~40-60K)

// ---------- K1: p, denomInv, cursors, err slots, ELL zero-fill ----------
__global__ void init_kernel(const float* __restrict__ x,
                            const float* __restrict__ ybus,
                            float* __restrict__ p,
                            float* __restrict__ denomInv,
                            int* __restrict__ cursor_nd,
                            int* __restrict__ cursor_f,
                            int* __restrict__ tailCur,
                            int4* __restrict__ ellZero,   // ellND+ellF contiguous
                            float* __restrict__ errOut) {
    const int ZTOT4 = (2 * W_ND * NN + 2 * W_F * NN) / 4;  // int4 count
    int tid = blockIdx.x * blockDim.x + threadIdx.x;
    int stride = gridDim.x * blockDim.x;
    for (int i = tid; i < NN; i += stride) {
        float2 xi = ((const float2*)x)[i];
        p[i] = xi.x - xi.y;
        int b = i / NBUS;
        int j = i - b * NBUS;
        denomInv[i] = 1.0f / (ybus[b * (NBUS * NBUS) + j * (NBUS + 1)] * 100.0f);
    }
    for (int i = tid; i < ZTOT4; i += stride) ellZero[i] = make_int4(0, 0, 0, 0);
    if (tid < 256) {
        cursor_nd[tid] = tid * CAP_ND;
        cursor_f[tid]  = tid * CAP_F;
    }
    if (tid < 2) tailCur[tid] = 0;
    if (tid < NLAYERS + 1) errOut[tid] = 0.0f;
}

// ---------- K2 (binA): tile -> LDS bin by coarse bucket -> chunked staging writes ----------
// staged entry: .x = src | (dstLocal<<19), .y = bits(w*100)
__global__ __launch_bounds__(256) void binA_kernel(
        const int* __restrict__ src_nd, const int* __restrict__ dst_nd,
        const float* __restrict__ ea_nd,
        const int* __restrict__ src_f, const int* __restrict__ dst_f,
        const float* __restrict__ ea_f,
        int* __restrict__ cursor_nd, int* __restrict__ cursor_f,
        uint2* __restrict__ stg_nd, uint2* __restrict__ stg_f) {
    __shared__ uint2 buf[TILE];            // 32 KB
    __shared__ unsigned char sb[TILE];     // 4 KB
    __shared__ int hist[256];
    __shared__ int scanA[256];
    __shared__ int segStart[256];
    __shared__ int segGBase[256];

    bool isF = blockIdx.x >= ND_TILES;
    int tile = isF ? (blockIdx.x - ND_TILES) : blockIdx.x;
    const int* src = isF ? src_f : src_nd;
    const int* dst = isF ? dst_f : dst_nd;
    const float* ea = isF ? ea_f : ea_nd;
    int* cursor = isF ? cursor_f : cursor_nd;
    uint2* stg = isF ? stg_f : stg_nd;
    int cap = isF ? CAP_F : CAP_ND;

    int tid = threadIdx.x;
    int base = tile * TILE;

    hist[tid] = 0;
    __syncthreads();

    #pragma unroll
    for (int k = 0; k < TILE / 256; ++k) {
        int d = dst[base + k * 256 + tid];
        atomicAdd(&hist[d >> SPAN_SHIFT], 1);
    }
    __syncthreads();

    int cnt = hist[tid];
    scanA[tid] = cnt;
    __syncthreads();
    for (int off = 1; off < 256; off <<= 1) {
        int t = (tid >= off) ? scanA[tid - off] : 0;
        __syncthreads();
        scanA[tid] += t;
        __syncthreads();
    }
    int excl = scanA[tid] - cnt;
    segStart[tid] = excl;
    hist[tid] = excl;
    if (tid < NBKT && cnt > 0) segGBase[tid] = atomicAdd(&cursor[tid], cnt);
    __syncthreads();

    #pragma unroll
    for (int k = 0; k < TILE / 256; ++k) {
        int e = base + k * 256 + tid;
        int d = dst[e];
        int bkt = d >> SPAN_SHIFT;
        int pos = atomicAdd(&hist[bkt], 1);
        unsigned dl = (unsigned)(d & SPAN_MASK);
        buf[pos] = make_uint2((unsigned)src[e] | (dl << 19),
                              (unsigned)__float_as_int(ea[e] * 100.0f));
        sb[pos] = (unsigned char)bkt;
    }
    __syncthreads();

    #pragma unroll
    for (int k = 0; k < TILE / 256; ++k) {
        int slot = k * 256 + tid;
        int bkt = sb[slot];
        int gpos = segGBase[bkt] + (slot - segStart[bkt]);
        if (gpos < (bkt + 1) * cap)  // freak-overflow guard
            stg[gpos] = buf[slot];
    }
}

// ---------- K3 (binB): per-bucket ELL build (column-major) + tail overflow ----------
__global__ __launch_bounds__(256) void binB_kernel(
        const uint2* __restrict__ stg_nd, const uint2* __restrict__ stg_f,
        const int* __restrict__ cursor_nd, const int* __restrict__ cursor_f,
        int2* __restrict__ ellND, int2* __restrict__ ellF,
        int2* __restrict__ tailND, int2* __restrict__ tailF,
        int* __restrict__ tailCur /* [0]=nd [1]=f */) {
    __shared__ int h[2048];    // per-local-node count
    __shared__ int rk[2048];   // per-local-node rank cursor
    __shared__ int tb[2048];   // per-local-node tail base (overflow rows only)

    bool isF = blockIdx.x >= NBKT;
    int bb = isF ? (blockIdx.x - NBKT) : blockIdx.x;
    const uint2* stg = isF ? stg_f : stg_nd;
    int cap = isF ? CAP_F : CAP_ND;
    int W = isF ? W_F : W_ND;
    int2* ell = isF ? ellF : ellND;
    int2* tail = isF ? tailF : tailND;
    int* tc = isF ? (tailCur + 1) : tailCur;
    int cnt_all = (isF ? cursor_f[bb] : cursor_nd[bb]) - bb * cap;
    if (cnt_all > cap) cnt_all = cap;
    int stgBase = bb * cap;
    int nodeBase = bb * 2048;
    int tid = threadIdx.x;

    #pragma unroll
    for (int k = 0; k < 8; ++k) { h[k * 256 + tid] = 0; rk[k * 256 + tid] = 0; }
    __syncthreads();

    // phase 1: per-node histogram
    for (int i = tid; i < cnt_all; i += 256) {
        uint2 v = stg[stgBase + i];
        atomicAdd(&h[(v.x >> 19) & SPAN_MASK], 1);
    }
    __syncthreads();

    // phase 2: tail allocation + descriptor for overflow rows (cnt > W)
    #pragma unroll
    for (int k = 0; k < 8; ++k) {
        int dl = k * 256 + tid;
        int c = h[dl];
        if (c > W) {
            int len = c - (W - 1);
            int tbase = atomicAdd(tc, len);
            if (tbase + len > TAILCAP) { tbase = 0; len = 0; }  // freak guard
            tb[dl] = tbase;
            ell[(W - 1) * NN + nodeBase + dl] =
                make_int2((int)(0x80000000u | (unsigned)len), tbase);
        }
    }
    __syncthreads();

    // phase 3: scatter staged -> ELL slots / tail
    for (int i = tid; i < cnt_all; i += 256) {
        uint2 v = stg[stgBase + i];
        int dl = (v.x >> 19) & SPAN_MASK;
        int c = h[dl];
        int r = atomicAdd(&rk[dl], 1);
        int plain = (c <= W) ? c : (W - 1);
        int2 pr = make_int2((int)(v.x & 0x7FFFF), (int)v.y);
        if (r < plain) ell[r * NN + nodeBase + dl] = pr;
        else {
            int pos = tb[dl] + r - plain;
            if (pos < TAILCAP) tail[pos] = pr;
        }
    }
}

// ---------- K4: layer 0 (theta = 0): out0 = p*denomInv - slack ----------
__global__ void out0_kernel(const float* __restrict__ p,
                            const float* __restrict__ denomInv,
                            float* __restrict__ out) {
    int b = blockIdx.x;
    int j = threadIdx.x;
    int i = b * NBUS + j;
    __shared__ float z0;
    float z = 0.0f;
    if (j < NBUS) z = p[i] * denomInv[i];
    if (j == 0) z0 = z;
    __syncthreads();
    if (j < NBUS) out[i] = z - z0;
}

// ---------- K5: fused layer: ELL gather nd -> out_k ; ELL gather f -> err_{k-1} ----------
template <bool DO_OUT>
__global__ __launch_bounds__(128) void layer_kernel(
        const int2* __restrict__ ellND, const int2* __restrict__ tailND,
        const int2* __restrict__ ellF, const int2* __restrict__ tailF,
        const float* __restrict__ cur,
        const float* __restrict__ p,
        const float* __restrict__ denomInv,
        float* __restrict__ out,
        float* __restrict__ errSlot) {
    int b = blockIdx.x;
    int j = threadIdx.x;
    int i = b * NBUS + j;
    bool act = j < NBUS;
    __shared__ float z0;
    __shared__ float ws2[2];

    float pv = 0.0f, di = 0.0f;
    float sum_nd = 0.0f, sum_f = 0.0f;
    if (act) {
        pv = p[i];
        if (DO_OUT) {
            di = denomInv[i];
            int2 e[W_ND];
            #pragma unroll
            for (int s = 0; s < W_ND - 1; ++s) e[s] = ellND[s * NN + i];
            #pragma unroll
            for (int s = 0; s < W_ND - 1; ++s)
                sum_nd += cur[e[s].x] * __int_as_float(e[s].y);
            int2 last = ellND[(W_ND - 1) * NN + i];
            if (last.x < 0) {  // tail descriptor
                int len = last.x & 0x7FFFFFFF;
                int tbase = last.y;
                for (int t = 0; t < len; ++t) {
                    int2 pr = tailND[tbase + t];
                    sum_nd += cur[pr.x] * __int_as_float(pr.y);
                }
            } else {
                sum_nd += cur[last.x] * __int_as_float(last.y);
            }
        }
        {
            int2 e[W_F];
            #pragma unroll
            for (int s = 0; s < W_F - 1; ++s) e[s] = ellF[s * NN + i];
            #pragma unroll
            for (int s = 0; s < W_F - 1; ++s)
                sum_f += cur[e[s].x] * __int_as_float(e[s].y);
            int2 last = ellF[(W_F - 1) * NN + i];
            if (last.x < 0) {
                int len = last.x & 0x7FFFFFFF;
                int tbase = last.y;
                for (int t = 0; t < len; ++t) {
                    int2 pr = tailF[tbase + t];
                    sum_f += cur[pr.x] * __int_as_float(pr.y);
                }
            } else {
                sum_f += cur[last.x] * __int_as_float(last.y);
            }
        }
    }
    if (DO_OUT) {
        float z = (pv - sum_nd) * di;
        if (j == 0) z0 = z;
        __syncthreads();
        if (act) out[i] = z - z0;
    }
    float acc = act ? fabsf(pv - sum_f) : 0.0f;
    for (int off = 32; off > 0; off >>= 1) acc += __shfl_down(acc, off, 64);
    if ((threadIdx.x & 63) == 0) ws2[threadIdx.x >> 6] = acc;
    __syncthreads();
    if (threadIdx.x == 0) atomicAdd(errSlot, ws2[0] + ws2[1]);
}

extern "C" void kernel_launch(void* const* d_in, const int* in_sizes, int n_in,
                              void* d_out, int out_size, void* d_ws, size_t ws_size,
                              hipStream_t stream) {
    const float* x     = (const float*)d_in[0];
    const int*   ei_nd = (const int*)d_in[2];
    const float* ea_nd = (const float*)d_in[3];
    const int*   ei    = (const int*)d_in[4];
    const float* ea    = (const float*)d_in[5];
    const float* ybus  = (const float*)d_in[6];

    float* out_f = (float*)d_out;
    float* errs  = out_f + NN;

    // workspace carve (4-byte units; keep ELL start 16B-aligned for int4 zero-fill)
    float* wsf       = (float*)d_ws;
    float* p         = wsf;          wsf += NN;
    float* denomInv  = wsf;          wsf += NN;
    float* outA      = wsf;          wsf += NN;
    float* outB      = wsf;          wsf += NN;
    int*   cursor_nd = (int*)wsf;    wsf += 256;
    int*   cursor_f  = (int*)wsf;    wsf += 256;
    int*   tailCur   = (int*)wsf;    wsf += 4;   // keeps 16B alignment (4NN+516 ≡ 0 mod 4)
    int2*  ellND     = (int2*)wsf;   wsf += 2LL * W_ND * NN;
    int2*  ellF      = (int2*)wsf;   wsf += 2LL * W_F * NN;
    int2*  tailND    = (int2*)wsf;   wsf += 2LL * TAILCAP;
    int2*  tailF     = (int2*)wsf;   wsf += 2LL * TAILCAP;
    uint2* stg_nd    = (uint2*)wsf;  wsf += 2LL * NBKT * CAP_ND;
    uint2* stg_f     = (uint2*)wsf;  wsf += 2LL * NBKT * CAP_F;

    const int* src_nd = ei_nd;
    const int* dst_nd = ei_nd + END_E;
    const int* src_f  = ei;
    const int* dst_f  = ei + EF_E;

    // ---- build phase ----
    init_kernel<<<2048, 256, 0, stream>>>(x, ybus, p, denomInv,
                                          cursor_nd, cursor_f, tailCur,
                                          (int4*)ellND, errs);
    binA_kernel<<<ND_TILES + F_TILES, 256, 0, stream>>>(
        src_nd, dst_nd, ea_nd, src_f, dst_f, ea,
        cursor_nd, cursor_f, stg_nd, stg_f);
    binB_kernel<<<2 * NBKT, 256, 0, stream>>>(
        stg_nd, stg_f, cursor_nd, cursor_f,
        ellND, ellF, tailND, tailF, tailCur);

    // ---- iterate phase ----
    out0_kernel<<<BATCH, 128, 0, stream>>>(p, denomInv, outA);
    const float* cur = outA;
    for (int k = 1; k <= NLAYERS; ++k) {
        float* nxt = (k == NLAYERS) ? out_f : ((k & 1) ? outB : outA);
        layer_kernel<true><<<BATCH, 128, 0, stream>>>(
            ellND, tailND, ellF, tailF, cur, p, denomInv, nxt, errs + (k - 1));
        cur = nxt;
    }
    layer_kernel<false><<<BATCH, 128, 0, stream>>>(
        ellND, tailND, ellF, tailF, cur, p, denomInv, nullptr, errs + NLAYERS);
}